// Round 9
// baseline (447.697 us; speedup 1.0000x reference)
//
#include <hip/hip_runtime.h>
#include <hip/hip_fp16.h>

// AxialAttention: N=2, C=128, H=W=128, G=8, gp=16 (v), 8 (q/k)
// k_attn v4: f16 K/V LDS (33KB -> 4 blocks/CU), f16 asv/sve accum (hfma2),
// exp pre-scaled by 1/1024. k_qkv v2: 128x64 tile, 8x4/thread, float4 Ws.

#define HW 16384   // H*W

__device__ __forceinline__ float warp_sum(float v) {
#pragma unroll
  for (int o = 32; o > 0; o >>= 1) v += __shfl_down(v, o);
  return v;
}

// ---------------- x transpose: per 128x128 plane ----------------
__global__ __launch_bounds__(256) void k_transpose(const float* __restrict__ in, float* __restrict__ out) {
  __shared__ float t[32][33];
  int plane = blockIdx.y;
  int th = (blockIdx.x >> 2) * 32;
  int tw = (blockIdx.x & 3) * 32;
  const float* p = in + (size_t)plane * HW;
  float* q = out + (size_t)plane * HW;
  int lx = threadIdx.x, ly = threadIdx.y;
#pragma unroll
  for (int r = ly; r < 32; r += 8) t[r][lx] = p[(th + r) * 128 + tw + lx];
  __syncthreads();
#pragma unroll
  for (int r = ly; r < 32; r += 8) q[(tw + r) * 128 + th + lx] = t[lx][r];
}

// ---------------- weight transpose: WT[c][och] 128x256 ----------------
__global__ __launch_bounds__(256) void k_wT(const float* __restrict__ wq, const float* __restrict__ wk,
                                            const float* __restrict__ wv, float* __restrict__ WT) {
  int idx = blockIdx.x * 256 + threadIdx.x;  // 32768 total
  int och = idx & 255, c = idx >> 8;
  const float* wrow = och < 64 ? wq + och * 128 : (och < 128 ? wk + (och - 64) * 128 : wv + (och - 128) * 128);
  WT[c * 256 + och] = wrow[c];
}

// ---------------- QKV GEMM v2: 128 och x 64 pix tile, 8x4 per thread ----------------
__global__ __launch_bounds__(256) void k_qkv(const float* __restrict__ xT, const float* __restrict__ WT,
                                             float* __restrict__ qkvT) {
  __shared__ float Xs[64][64];   // [k][pix]  16 KB
  __shared__ float Ws[64][128];  // [k][och]  32 KB
  int pb = blockIdx.x * 64;
  int ob = blockIdx.y * 128;
  int b = blockIdx.z;
  const float* xb = xT + (size_t)b * (128 * HW);
  int tid = threadIdx.x;
  int tx = tid & 15, ty = tid >> 4;  // tx: pix group (4), ty: och group (8)
  float acc[8][4] = {};
  for (int ks = 0; ks < 2; ++ks) {
    for (int idx = tid; idx < 4096; idx += 256) {
      int c = idx >> 6, p = idx & 63;
      Xs[c][p] = xb[(ks * 64 + c) * HW + pb + p];
    }
    for (int idx = tid; idx < 8192; idx += 256) {
      int c = idx >> 7, o = idx & 127;
      Ws[c][o] = WT[(ks * 64 + c) * 256 + ob + o];
    }
    __syncthreads();
#pragma unroll 4
    for (int kk = 0; kk < 64; ++kk) {
      float4 a0 = *reinterpret_cast<const float4*>(&Ws[kk][ty * 8]);
      float4 a1 = *reinterpret_cast<const float4*>(&Ws[kk][ty * 8 + 4]);
      float4 bv = *reinterpret_cast<const float4*>(&Xs[kk][tx * 4]);
      acc[0][0] += a0.x * bv.x; acc[0][1] += a0.x * bv.y; acc[0][2] += a0.x * bv.z; acc[0][3] += a0.x * bv.w;
      acc[1][0] += a0.y * bv.x; acc[1][1] += a0.y * bv.y; acc[1][2] += a0.y * bv.z; acc[1][3] += a0.y * bv.w;
      acc[2][0] += a0.z * bv.x; acc[2][1] += a0.z * bv.y; acc[2][2] += a0.z * bv.z; acc[2][3] += a0.z * bv.w;
      acc[3][0] += a0.w * bv.x; acc[3][1] += a0.w * bv.y; acc[3][2] += a0.w * bv.z; acc[3][3] += a0.w * bv.w;
      acc[4][0] += a1.x * bv.x; acc[4][1] += a1.x * bv.y; acc[4][2] += a1.x * bv.z; acc[4][3] += a1.x * bv.w;
      acc[5][0] += a1.y * bv.x; acc[5][1] += a1.y * bv.y; acc[5][2] += a1.y * bv.z; acc[5][3] += a1.y * bv.w;
      acc[6][0] += a1.z * bv.x; acc[6][1] += a1.z * bv.y; acc[6][2] += a1.z * bv.z; acc[6][3] += a1.z * bv.w;
      acc[7][0] += a1.w * bv.x; acc[7][1] += a1.w * bv.y; acc[7][2] += a1.w * bv.z; acc[7][3] += a1.w * bv.w;
    }
    __syncthreads();
  }
#pragma unroll
  for (int r = 0; r < 8; ++r) {
    int row = ob + ty * 8 + r;
    float4 o4 = make_float4(acc[r][0], acc[r][1], acc[r][2], acc[r][3]);
    *reinterpret_cast<float4*>(&qkvT[(size_t)(b * 256 + row) * HW + pb + tx * 4]) = o4;
  }
}

// ---------------- per-channel stats of raw q/k/v ----------------
__global__ __launch_bounds__(256) void k_qkv_stats(const float* __restrict__ qkvT, double* __restrict__ statsQKV) {
  __shared__ float r1[4], r2[4];
  int ch = blockIdx.x;  // 0..255
  float s = 0.f, s2 = 0.f;
  for (int b = 0; b < 2; ++b) {
    const float* p = qkvT + (size_t)(b * 256 + ch) * HW;
    for (int idx = threadIdx.x; idx < HW; idx += 256) { float v = p[idx]; s += v; s2 += v * v; }
  }
  s = warp_sum(s); s2 = warp_sum(s2);
  int wid = threadIdx.x >> 6;
  if ((threadIdx.x & 63) == 0) { r1[wid] = s; r2[wid] = s2; }
  __syncthreads();
  if (threadIdx.x == 0) {
    statsQKV[2 * ch]     = (double)(r1[0] + r1[1] + r1[2] + r1[3]);
    statsQKV[2 * ch + 1] = (double)(r2[0] + r2[1] + r2[2] + r2[3]);
  }
}

// ---------------- rel tables for analytic stats ----------------
__global__ __launch_bounds__(128) void k_rel_tables(const float* __restrict__ q_rel, const float* __restrict__ k_rel,
                                                    float* __restrict__ tabs) {
  int tbl = blockIdx.x / 44, item = blockIdx.x % 44;
  const float* rel = tbl ? k_rel : q_rel;
  float* out = tabs + tbl * 5632;
  int i = threadIdx.x;  // 0..127
  float s = 0.f;
  if (item < 8) {
    const float* r = rel + item * 255 + i;
    for (int d = 0; d < 128; ++d) s += r[d];
  } else {
    int p = item - 8;
    int pp = p, c = 0;
    while (pp >= 8 - c) { pp -= 8 - c; ++c; }
    int c2 = c + pp;
    const float* ra = rel + c * 255 + i;
    const float* rb = rel + c2 * 255 + i;
    for (int d = 0; d < 128; ++d) s += ra[d] * rb[d];
  }
  out[item * 128 + i] = s;
}

// ---------------- analytic stats of qk/qr/kr via per-slice Gram matrices ----------------
__global__ __launch_bounds__(128) void k_qkr_stats(
    const float* __restrict__ qkvT, const double* __restrict__ statsQKV,
    const float* __restrict__ bnq_g, const float* __restrict__ bnq_b,
    const float* __restrict__ bnk_g, const float* __restrict__ bnk_b,
    const float* __restrict__ tabs, double* __restrict__ statsA) {
  __shared__ float red[92][2];
  int slice = blockIdx.x;  // (b*8+g)*128 + w
  int w = slice & 127, g = (slice >> 7) & 7, b = slice >> 10;
  int i = threadIdx.x;  // 0..127
  float qn[8], kn[8];
  const float* qbase = qkvT + (size_t)(b * 256 + g * 8) * HW + w * 128 + i;
  const float* kbase = qkvT + (size_t)(b * 256 + 64 + g * 8) * HW + w * 128 + i;
#pragma unroll
  for (int c = 0; c < 8; ++c) {
    {
      int och = g * 8 + c;
      double su = statsQKV[2 * och], sq = statsQKV[2 * och + 1];
      double mu = su * (1.0 / 32768.0);
      float var = (float)(sq * (1.0 / 32768.0) - mu * mu);
      float sc = bnq_g[och] * rsqrtf(var + 1e-5f);
      qn[c] = qbase[c * HW] * sc + (bnq_b[och] - (float)mu * sc);
    }
    {
      int gi = g * 8 + c, och = 64 + gi;
      double su = statsQKV[2 * och], sq = statsQKV[2 * och + 1];
      double mu = su * (1.0 / 32768.0);
      float var = (float)(sq * (1.0 / 32768.0) - mu * mu);
      float sc = bnk_g[gi] * rsqrtf(var + 1e-5f);
      kn[c] = kbase[c * HW] * sc + (bnk_b[gi] - (float)mu * sc);
    }
  }
  float vals[92];
  int n = 0;
#pragma unroll
  for (int c = 0; c < 8; ++c) vals[n++] = qn[c];
#pragma unroll
  for (int c = 0; c < 8; ++c) vals[n++] = kn[c];
#pragma unroll
  for (int c = 0; c < 8; ++c)
#pragma unroll
    for (int c2 = c; c2 < 8; ++c2) vals[n++] = qn[c] * qn[c2];
#pragma unroll
  for (int c = 0; c < 8; ++c)
#pragma unroll
    for (int c2 = c; c2 < 8; ++c2) vals[n++] = kn[c] * kn[c2];
  float sqr = 0.f, s2qr = 0.f, skr = 0.f, s2kr = 0.f;
#pragma unroll
  for (int c = 0; c < 8; ++c) {
    sqr += qn[c] * tabs[c * 128 + i];
    skr += kn[c] * tabs[5632 + c * 128 + i];
  }
  {
    int p = 0;
#pragma unroll
    for (int c = 0; c < 8; ++c)
#pragma unroll
      for (int c2 = c; c2 < 8; ++c2) {
        float f = (c == c2) ? 1.f : 2.f;
        s2qr += f * qn[c] * qn[c2] * tabs[1024 + p * 128 + i];
        s2kr += f * kn[c] * kn[c2] * tabs[5632 + 1024 + p * 128 + i];
        ++p;
      }
  }
  vals[88] = sqr; vals[89] = s2qr; vals[90] = skr; vals[91] = s2kr;
  int lane = i & 63, wid = i >> 6;
#pragma unroll
  for (int vv = 0; vv < 92; ++vv) {
    float r = warp_sum(vals[vv]);
    if (lane == 0) red[vv][wid] = r;
  }
  __syncthreads();
  if (i == 0) {
    float f[92];
#pragma unroll
    for (int vv = 0; vv < 92; ++vv) f[vv] = red[vv][0] + red[vv][1];
    float sS = 0.f, s2S = 0.f;
#pragma unroll
    for (int c = 0; c < 8; ++c) sS += f[c] * f[8 + c];
    {
      int p = 0;
#pragma unroll
      for (int c = 0; c < 8; ++c)
#pragma unroll
        for (int c2 = c; c2 < 8; ++c2) { float fm = (c == c2) ? 1.f : 2.f; s2S += fm * f[16 + p] * f[52 + p]; ++p; }
    }
    atomicAdd(&statsA[(0 * 8 + g) * 2 + 0], (double)sS);
    atomicAdd(&statsA[(0 * 8 + g) * 2 + 1], (double)s2S);
    atomicAdd(&statsA[(1 * 8 + g) * 2 + 0], (double)f[88]);
    atomicAdd(&statsA[(1 * 8 + g) * 2 + 1], (double)f[89]);
    atomicAdd(&statsA[(2 * 8 + g) * 2 + 0], (double)f[90]);
    atomicAdd(&statsA[(2 * 8 + g) * 2 + 1], (double)f[91]);
  }
}

// ---------------- q_rel/k_rel -> [d][c] transposed (runs after k_qkr_stats; reuses tabs) ----------------
__global__ __launch_bounds__(256) void k_relT(const float* __restrict__ q_rel, const float* __restrict__ k_rel,
                                              float* __restrict__ relT) {
  int idx = blockIdx.x * 256 + threadIdx.x;  // 4080 total
  if (idx < 2040) {
    int d = idx >> 3, c = idx & 7;
    relT[idx] = q_rel[c * 255 + d];
  } else if (idx < 4080) {
    int j = idx - 2040;
    int d = j >> 3, c = j & 7;
    relT[2040 + j] = k_rel[c * 255 + d];
  }
}

// ---------------- fused attention v4: f16 K/V LDS, 4 slices/block, 2 rows/thread ----------------
__global__ __launch_bounds__(256, 4) void k_attn(
    const float* __restrict__ qkvT,
    const double* __restrict__ statsQKV, const double* __restrict__ statsA,
    const float* __restrict__ relTq, const float* __restrict__ relTk, const float* __restrict__ v_rel,
    const float* __restrict__ bnq_g, const float* __restrict__ bnq_b,
    const float* __restrict__ bnk_g, const float* __restrict__ bnk_b,
    const float* __restrict__ bnv_g, const float* __restrict__ bnv_b,
    const float* __restrict__ bnqk_g, const float* __restrict__ bnqk_b,
    const float* __restrict__ bnqr_g, const float* __restrict__ bnqr_b,
    const float* __restrict__ bnkr_g, const float* __restrict__ bnkr_b,
    float* __restrict__ svT, float* __restrict__ sveT) {
  __shared__ __half Ks[4][128][8];   // [slice][j][c] normalized K f16, 16B rows (8 KB)
  __shared__ __half Vs[4][128][16];  // [slice][j][c] normalized V f16, 32B rows (16 KB)
  __shared__ __half Wh[2][255][8];   // chunked f16 v_rel, 16B rows -> conflict-free gather (8 KB)
  __shared__ float nsc[32], nsh[32];
  int tid = threadIdx.x;
  int slice0 = blockIdx.x * 4;
  int w0 = slice0 & 127, g = (slice0 >> 7) & 7, b = slice0 >> 10;  // (b,g) uniform over the 4 slices
  if (tid < 32) {
    int och, gi; const float* gm; const float* bt;
    if (tid < 8)       { gi = g * 8 + tid;        och = gi;       gm = bnq_g; bt = bnq_b; }
    else if (tid < 16) { gi = g * 8 + (tid - 8);  och = 64 + gi;  gm = bnk_g; bt = bnk_b; }
    else               { gi = g * 16 + (tid - 16); och = 128 + gi; gm = bnv_g; bt = bnv_b; }
    double su = statsQKV[2 * och], sq = statsQKV[2 * och + 1];
    double mu = su * (1.0 / 32768.0);
    float var = (float)(sq * (1.0 / 32768.0) - mu * mu);
    float sc = gm[gi] * rsqrtf(var + 1e-5f);
    nsc[tid] = sc;
    nsh[tid] = bt[gi] - (float)mu * sc;
  }
  __syncthreads();
  for (int idx = tid; idx < 4096; idx += 256) {
    int j = idx & 127, c = (idx >> 7) & 7, s = idx >> 10;
    Ks[s][j][c] = __float2half(
        qkvT[(size_t)(b * 256 + 64 + g * 8 + c) * HW + (w0 + s) * 128 + j] * nsc[8 + c] + nsh[8 + c]);
  }
  for (int idx = tid; idx < 8192; idx += 256) {
    int j = idx & 127, c = (idx >> 7) & 15, s = idx >> 11;
    Vs[s][j][c] = __float2half(
        qkvT[(size_t)(b * 256 + 128 + g * 16 + c) * HW + (w0 + s) * 128 + j] * nsc[16 + c] + nsh[16 + c]);
  }
  for (int idx = tid; idx < 4080; idx += 256) {
    int c8 = idx / 2040, r = idx - c8 * 2040, d = r >> 3, e = r & 7;
    Wh[c8][d][e] = __float2half(v_rel[(c8 * 8 + e) * 255 + d]);
  }
  float aS, aQR, aKR, offs;
  {
    const double inv = 1.0 / 4194304.0;  // N*H*H*W per group
    double s0 = statsA[(0 * 8 + g) * 2], q0 = statsA[(0 * 8 + g) * 2 + 1];
    double s1 = statsA[(1 * 8 + g) * 2], q1 = statsA[(1 * 8 + g) * 2 + 1];
    double s2 = statsA[(2 * 8 + g) * 2], q2 = statsA[(2 * 8 + g) * 2 + 1];
    double m0 = s0 * inv, m1 = s1 * inv, m2 = s2 * inv;
    float v0 = (float)(q0 * inv - m0 * m0);
    float v1 = (float)(q1 * inv - m1 * m1);
    float v2 = (float)(q2 * inv - m2 * m2);
    aS  = bnqk_g[g] * rsqrtf(v0 + 1e-5f);
    aQR = bnqr_g[g] * rsqrtf(v1 + 1e-5f);
    aKR = bnkr_g[g] * rsqrtf(v2 + 1e-5f);
    offs = (bnqk_b[g] - (float)m0 * aS) + (bnqr_b[g] - (float)m1 * aQR) + (bnkr_b[g] - (float)m2 * aKR);
    offs -= 6.931471805599453f;  // *1/1024 on all exp(): softmax-invariant, guards f16 accum overflow
  }
  __syncthreads();

  int wv = tid >> 6, lane = tid & 63;
  int slice = slice0 + wv, w = w0 + wv;
  int i0 = lane, i1 = lane + 64;
  float q0r[8], q1r[8];
  {
    const float* qbase = qkvT + (size_t)(b * 256 + g * 8) * HW + w * 128;
#pragma unroll
    for (int c = 0; c < 8; ++c) {
      q0r[c] = qbase[c * HW + i0] * nsc[c] + nsh[c];
      q1r[c] = qbase[c * HW + i1] * nsc[c] + nsh[c];
    }
  }
  float l0 = 0.f, l1 = 0.f;
  __half2 av0[8], av1[8], ha0[8], ha1[8];
#pragma unroll
  for (int u = 0; u < 8; ++u) {
    av0[u] = __float2half2_rn(0.f); av1[u] = __float2half2_rn(0.f);
    ha0[u] = __float2half2_rn(0.f); ha1[u] = __float2half2_rn(0.f);
  }
  const __half* Kp = &Ks[wv][0][0];
  const __half* Vp = &Vs[wv][0][0];

#pragma unroll 2
  for (int j = 0; j < 128; ++j) {
    // K row: one b128, unpack 8 halves -> f32 (shared by S and KR, both rows)
    float4 kraw = *reinterpret_cast<const float4*>(Kp + j * 8);
    const __half2* kh = reinterpret_cast<const __half2*>(&kraw);
    float2 k01 = __half22float2(kh[0]);
    float2 k23 = __half22float2(kh[1]);
    float2 k45 = __half22float2(kh[2]);
    float2 k67 = __half22float2(kh[3]);
    int dq = 127 + i0 - j;   // qr row (i0); i1 row = dq+64
    int d0 = 127 - i0 + j;   // kr & v_rel row (i0); i1 row = d0-64
    const float4* qp0 = reinterpret_cast<const float4*>(relTq + dq * 8);
    const float4* qp1 = reinterpret_cast<const float4*>(relTq + (dq + 64) * 8);
    const float4* rp0 = reinterpret_cast<const float4*>(relTk + d0 * 8);
    const float4* rp1 = reinterpret_cast<const float4*>(relTk + (d0 - 64) * 8);
    float4 qa0 = qp0[0], qb0 = qp0[1], qa1 = qp1[0], qb1 = qp1[1];
    float4 ra0 = rp0[0], rb0 = rp0[1], ra1 = rp1[0], rb1 = rp1[1];
    float S0 = q0r[0]*k01.x + q0r[1]*k01.y + q0r[2]*k23.x + q0r[3]*k23.y
             + q0r[4]*k45.x + q0r[5]*k45.y + q0r[6]*k67.x + q0r[7]*k67.y;
    float S1 = q1r[0]*k01.x + q1r[1]*k01.y + q1r[2]*k23.x + q1r[3]*k23.y
             + q1r[4]*k45.x + q1r[5]*k45.y + q1r[6]*k67.x + q1r[7]*k67.y;
    float QR0 = q0r[0]*qa0.x + q0r[1]*qa0.y + q0r[2]*qa0.z + q0r[3]*qa0.w
              + q0r[4]*qb0.x + q0r[5]*qb0.y + q0r[6]*qb0.z + q0r[7]*qb0.w;
    float QR1 = q1r[0]*qa1.x + q1r[1]*qa1.y + q1r[2]*qa1.z + q1r[3]*qa1.w
              + q1r[4]*qb1.x + q1r[5]*qb1.y + q1r[6]*qb1.z + q1r[7]*qb1.w;
    float KR0 = k01.x*ra0.x + k01.y*ra0.y + k23.x*ra0.z + k23.y*ra0.w
              + k45.x*rb0.x + k45.y*rb0.y + k67.x*rb0.z + k67.y*rb0.w;
    float KR1 = k01.x*ra1.x + k01.y*ra1.y + k23.x*ra1.z + k23.y*ra1.w
              + k45.x*rb1.x + k45.y*rb1.y + k67.x*rb1.z + k67.y*rb1.w;
    float a0 = fmaf(S0, aS, fmaf(QR0, aQR, fmaf(KR0, aKR, offs)));
    float a1 = fmaf(S1, aS, fmaf(QR1, aQR, fmaf(KR1, aKR, offs)));
    float e0 = __expf(a0);
    float e1 = __expf(a1);
    l0 += e0; l1 += e1;
    __half2 eh0 = __float2half2_rn(e0), eh1 = __float2half2_rn(e1);
    // V row: 2 b128 (16 halves), packed accumulate
    float4 vraw0 = *reinterpret_cast<const float4*>(Vp + j * 16);
    float4 vraw1 = *reinterpret_cast<const float4*>(Vp + j * 16 + 8);
    const __half2* vh0 = reinterpret_cast<const __half2*>(&vraw0);
    const __half2* vh1 = reinterpret_cast<const __half2*>(&vraw1);
    av0[0] = __hfma2(eh0, vh0[0], av0[0]); av0[1] = __hfma2(eh0, vh0[1], av0[1]);
    av0[2] = __hfma2(eh0, vh0[2], av0[2]); av0[3] = __hfma2(eh0, vh0[3], av0[3]);
    av0[4] = __hfma2(eh0, vh1[0], av0[4]); av0[5] = __hfma2(eh0, vh1[1], av0[5]);
    av0[6] = __hfma2(eh0, vh1[2], av0[6]); av0[7] = __hfma2(eh0, vh1[3], av0[7]);
    av1[0] = __hfma2(eh1, vh0[0], av1[0]); av1[1] = __hfma2(eh1, vh0[1], av1[1]);
    av1[2] = __hfma2(eh1, vh0[2], av1[2]); av1[3] = __hfma2(eh1, vh0[3], av1[3]);
    av1[4] = __hfma2(eh1, vh1[0], av1[4]); av1[5] = __hfma2(eh1, vh1[1], av1[5]);
    av1[6] = __hfma2(eh1, vh1[2], av1[6]); av1[7] = __hfma2(eh1, vh1[3], av1[7]);
    // v_rel gathers: 16B rows, consecutive-d lanes -> conflict-free b128
    float4 wa0 = *reinterpret_cast<const float4*>(&Wh[0][d0][0]);
    float4 wb0 = *reinterpret_cast<const float4*>(&Wh[1][d0][0]);
    float4 wa1 = *reinterpret_cast<const float4*>(&Wh[0][d0 - 64][0]);
    float4 wb1 = *reinterpret_cast<const float4*>(&Wh[1][d0 - 64][0]);
    {
      const __half2* pa = reinterpret_cast<const __half2*>(&wa0);
      const __half2* pb = reinterpret_cast<const __half2*>(&wb0);
      ha0[0] = __hfma2(eh0, pa[0], ha0[0]); ha0[1] = __hfma2(eh0, pa[1], ha0[1]);
      ha0[2] = __hfma2(eh0, pa[2], ha0[2]); ha0[3] = __hfma2(eh0, pa[3], ha0[3]);
      ha0[4] = __hfma2(eh0, pb[0], ha0[4]); ha0[5] = __hfma2(eh0, pb[1], ha0[5]);
      ha0[6] = __hfma2(eh0, pb[2], ha0[6]); ha0[7] = __hfma2(eh0, pb[3], ha0[7]);
    }
    {
      const __half2* pa = reinterpret_cast<const __half2*>(&wa1);
      const __half2* pb = reinterpret_cast<const __half2*>(&wb1);
      ha1[0] = __hfma2(eh1, pa[0], ha1[0]); ha1[1] = __hfma2(eh1, pa[1], ha1[1]);
      ha1[2] = __hfma2(eh1, pa[2], ha1[2]); ha1[3] = __hfma2(eh1, pa[3], ha1[3]);
      ha1[4] = __hfma2(eh1, pb[0], ha1[4]); ha1[5] = __hfma2(eh1, pb[1], ha1[5]);
      ha1[6] = __hfma2(eh1, pb[2], ha1[6]); ha1[7] = __hfma2(eh1, pb[3], ha1[7]);
    }
  }
  float li0 = 1.f / l0, li1 = 1.f / l1;
  float* osv0  = svT  + (size_t)slice * 2048 + i0;
  float* osve0 = sveT + (size_t)slice * 2048 + i0;
  float* osv1  = svT  + (size_t)slice * 2048 + i1;
  float* osve1 = sveT + (size_t)slice * 2048 + i1;
#pragma unroll
  for (int c = 0; c < 16; ++c) {
    float a0f = (c & 1) ? __high2float(av0[c >> 1]) : __low2float(av0[c >> 1]);
    float a1f = (c & 1) ? __high2float(av1[c >> 1]) : __low2float(av1[c >> 1]);
    float h0 = (c & 1) ? __high2float(ha0[c >> 1]) : __low2float(ha0[c >> 1]);
    float h1 = (c & 1) ? __high2float(ha1[c >> 1]) : __low2float(ha1[c >> 1]);
    osv0[c * 128]  = a0f * li0;
    osve0[c * 128] = h0 * li0;
    osv1[c * 128]  = a1f * li1;
    osve1[c * 128] = h1 * li1;
  }
}

// ---------------- per-channel stats of sv/sve ----------------
__global__ __launch_bounds__(256) void k_sv_stats(const float* __restrict__ svT, const float* __restrict__ sveT,
                                                  double* __restrict__ statsSV) {
  __shared__ float r1[4], r2[4];
  int ch = blockIdx.x;  // 0-127 sv, 128-255 sve
  const float* base = (ch < 128) ? svT : sveT;
  int c = ch & 127, g = c >> 4, cc = c & 15;
  float s = 0.f, s2 = 0.f;
  for (int idx = threadIdx.x; idx < 32768; idx += 256) {
    int bw = idx >> 7, ii = idx & 127;
    int bb = bw >> 7, wwi = bw & 127;
    float v = base[(size_t)(((bb * 8 + g) * 128) + wwi) * 2048 + cc * 128 + ii];
    s += v; s2 += v * v;
  }
  s = warp_sum(s); s2 = warp_sum(s2);
  int wid = threadIdx.x >> 6;
  if ((threadIdx.x & 63) == 0) { r1[wid] = s; r2[wid] = s2; }
  __syncthreads();
  if (threadIdx.x == 0) {
    statsSV[2 * ch]     = (double)(r1[0] + r1[1] + r1[2] + r1[3]);
    statsSV[2 * ch + 1] = (double)(r2[0] + r2[1] + r2[2] + r2[3]);
  }
}

// ---------------- final: out = bn(sv)+bn(sve), transpose (w,i)->(i,w) ----------------
__global__ __launch_bounds__(256) void k_final(const float* __restrict__ svT, const float* __restrict__ sveT,
                                               const double* __restrict__ statsSV,
                                               const float* __restrict__ bnsv_g, const float* __restrict__ bnsv_b,
                                               const float* __restrict__ bnsve_g, const float* __restrict__ bnsve_b,
                                               float* __restrict__ out) {
  __shared__ float t[32][33];
  int plane = blockIdx.y;  // b*128 + c
  int b = plane >> 7, c = plane & 127;
  int g = c >> 4, cc = c & 15;
  double s = statsSV[2 * c], s2 = statsSV[2 * c + 1];
  double mu1 = s * (1.0 / 32768.0);
  float var1 = (float)(s2 * (1.0 / 32768.0) - mu1 * mu1);
  float sc1 = bnsv_g[c] * rsqrtf(var1 + 1e-5f);
  float sh1 = bnsv_b[c] - (float)mu1 * sc1;
  double se = statsSV[2 * (128 + c)], se2 = statsSV[2 * (128 + c) + 1];
  double mu2 = se * (1.0 / 32768.0);
  float var2 = (float)(se2 * (1.0 / 32768.0) - mu2 * mu2);
  float sc2 = bnsve_g[c] * rsqrtf(var2 + 1e-5f);
  float sh2 = bnsve_b[c] - (float)mu2 * sc2;
  int tw = (blockIdx.x & 3) * 32, ti = (blockIdx.x >> 2) * 32;
  int lx = threadIdx.x, ly = threadIdx.y;
#pragma unroll
  for (int r = ly; r < 32; r += 8) {
    int wr = tw + r, ii = ti + lx;
    size_t off = (size_t)((b * 8 + g) * 128 + wr) * 2048 + cc * 128 + ii;
    t[r][lx] = svT[off] * sc1 + sh1 + sveT[off] * sc2 + sh2;
  }
  __syncthreads();
#pragma unroll
  for (int r = ly; r < 32; r += 8)
    out[(size_t)plane * HW + (ti + r) * 128 + tw + lx] = t[lx][r];
}

extern "C" void kernel_launch(void* const* d_in, const int* in_sizes, int n_in,
                              void* d_out, int out_size, void* d_ws, size_t ws_size,
                              hipStream_t stream) {
  const float* x      = (const float*)d_in[0];
  const float* wq     = (const float*)d_in[1];
  const float* wk     = (const float*)d_in[2];
  const float* wv     = (const float*)d_in[3];
  const float* q_rel  = (const float*)d_in[4];
  const float* k_rel  = (const float*)d_in[5];
  const float* v_rel  = (const float*)d_in[6];
  const float* bnq_g  = (const float*)d_in[7];
  const float* bnq_b  = (const float*)d_in[8];
  const float* bnk_g  = (const float*)d_in[9];
  const float* bnk_b  = (const float*)d_in[10];
  const float* bnv_g  = (const float*)d_in[11];
  const float* bnv_b  = (const float*)d_in[12];
  const float* bnqk_g = (const float*)d_in[13];
  const float* bnqk_b = (const float*)d_in[14];
  const float* bnqr_g = (const float*)d_in[15];
  const float* bnqr_b = (const float*)d_in[16];
  const float* bnkr_g = (const float*)d_in[17];
  const float* bnkr_b = (const float*)d_in[18];
  const float* bnsv_g = (const float*)d_in[19];
  const float* bnsv_b = (const float*)d_in[20];
  const float* bnsve_g = (const float*)d_in[21];
  const float* bnsve_b = (const float*)d_in[22];
  float* out = (float*)d_out;

  float* wsf  = (float*)d_ws;
  float* xT   = wsf;              // 4,194,304 floats (reused as svT later: lifetimes disjoint)
  float* svT  = wsf;
  float* qkvT = wsf + 4194304;    // 8,388,608 floats
  float* sveT = wsf + 12582912;   // 4,194,304 floats
  float* tabs = wsf + 16777216;   // 11,264 floats; after k_qkr_stats reused as relT (4,080 floats)
  float* relTq = tabs;
  float* relTk = tabs + 2040;
  float* WT   = wsf + 16788480;   // 32,768 floats
  double* statsQKV = (double*)(wsf + 16821248);  // 512 doubles
  double* statsA   = statsQKV + 512;             // 48 doubles
  double* statsSV  = statsA + 48;                // 512 doubles

  hipMemsetAsync(statsA, 0, 48 * sizeof(double), stream);
  k_transpose<<<dim3(16, 256), dim3(32, 8), 0, stream>>>(x, xT);
  k_wT<<<128, 256, 0, stream>>>(wq, wk, wv, WT);
  k_qkv<<<dim3(256, 2, 2), 256, 0, stream>>>(xT, WT, qkvT);
  k_qkv_stats<<<256, 256, 0, stream>>>(qkvT, statsQKV);
  k_rel_tables<<<88, 128, 0, stream>>>(q_rel, k_rel, tabs);
  k_qkr_stats<<<2048, 128, 0, stream>>>(qkvT, statsQKV, bnq_g, bnq_b, bnk_g, bnk_b, tabs, statsA);
  k_relT<<<16, 256, 0, stream>>>(q_rel, k_rel, relTq);  // overwrites tabs (dead after k_qkr_stats)
  k_attn<<<512, 256, 0, stream>>>(qkvT, statsQKV, statsA, relTq, relTk, v_rel,
                                  bnq_g, bnq_b, bnk_g, bnk_b, bnv_g, bnv_b,
                                  bnqk_g, bnqk_b, bnqr_g, bnqr_b, bnkr_g, bnkr_b,
                                  svT, sveT);
  k_sv_stats<<<256, 256, 0, stream>>>(svT, sveT, statsSV);
  k_final<<<dim3(16, 256), dim3(32, 8), 0, stream>>>(svT, sveT, statsSV,
                                                     bnsv_g, bnsv_b, bnsve_g, bnsve_b, out);
  (void)in_sizes; (void)n_in; (void)out_size; (void)ws_size;
}